// Round 1
// baseline (1833.137 us; speedup 1.0000x reference)
//
#include <hip/hip_runtime.h>
#include <math.h>

#define NTOK 131072
#define HDIM 256
#define DDIM 512
#define FDIM 1024
#define EDIM 16
#define TBLK 128
#define FCH  128
#define KCH  32

__global__ __launch_bounds__(256, 2)
void router_fused(const float* __restrict__ inp,
                  const float* __restrict__ cnd,
                  const float* __restrict__ W1,
                  const float* __restrict__ b1,
                  const float* __restrict__ W2,
                  const float* __restrict__ b2,
                  float* __restrict__ out)
{
    __shared__ float xs[KCH][TBLK + 4];     // x tile, k-major: xs[k][t]
    __shared__ float w1s[KCH][FCH + 4];     // W1 tile: w1s[k][f]
    __shared__ float lgt[TBLK][EDIM + 1];   // logits accumulator

    const int tid = threadIdx.x;
    const int ty  = tid >> 4;   // 0..15 token group (8 tokens each)
    const int tx  = tid & 15;   // 0..15 f group (8 cols each)
    const int t0  = blockIdx.x * TBLK;

    // init logits with b2 (exact owner-write, completed before first barrier)
    for (int i = tid; i < TBLK * EDIM; i += 256)
        lgt[i >> 4][i & 15] = b2[i & 15];

    float acc[8][8];

    for (int fc = 0; fc < FDIM; fc += FCH) {
#pragma unroll
        for (int i = 0; i < 8; ++i)
#pragma unroll
            for (int j = 0; j < 8; ++j) acc[i][j] = 0.0f;

        for (int kc = 0; kc < DDIM; kc += KCH) {
            __syncthreads();
            // ---- stage x tile (transposed into xs[k][t]) ----
            {
                const float* src = (kc < HDIM)
                    ? (inp + (size_t)t0 * HDIM + kc)
                    : (cnd + (size_t)t0 * HDIM + (kc - HDIM));
                const int kl = (tid & 7) * 4;   // 0..28
                const int tl = tid >> 3;        // 0..31
#pragma unroll
                for (int p = 0; p < 4; ++p) {
                    const int trow = tl + p * 32;
                    const float4 v = *(const float4*)(src + (size_t)trow * HDIM + kl);
                    xs[kl + 0][trow] = v.x;
                    xs[kl + 1][trow] = v.y;
                    xs[kl + 2][trow] = v.z;
                    xs[kl + 3][trow] = v.w;
                }
            }
            // ---- stage W1 tile ----
            {
                const int fl = (tid & 31) * 4;  // 0..124
                const int kl = tid >> 5;        // 0..7
#pragma unroll
                for (int p = 0; p < 4; ++p) {
                    const int krow = kl + p * 8;
                    *(float4*)&w1s[krow][fl] =
                        *(const float4*)(W1 + (size_t)(kc + krow) * FDIM + fc + fl);
                }
            }
            __syncthreads();
            // ---- 128x128x32 register-blocked FMA ----
#pragma unroll 8
            for (int k = 0; k < KCH; ++k) {
                const float4 a0 = *(const float4*)&xs[k][ty * 8];
                const float4 a1 = *(const float4*)&xs[k][ty * 8 + 4];
                const float4 b0 = *(const float4*)&w1s[k][tx * 8];
                const float4 b4 = *(const float4*)&w1s[k][tx * 8 + 4];
                const float av[8] = {a0.x, a0.y, a0.z, a0.w, a1.x, a1.y, a1.z, a1.w};
                const float bv[8] = {b0.x, b0.y, b0.z, b0.w, b4.x, b4.y, b4.z, b4.w};
#pragma unroll
                for (int i = 0; i < 8; ++i)
#pragma unroll
                    for (int j = 0; j < 8; ++j)
                        acc[i][j] = fmaf(av[i], bv[j], acc[i][j]);
            }
        }

        // ---- bias + exact GELU ----
        float bias[8];
        *(float4*)&bias[0] = *(const float4*)(b1 + fc + tx * 8);
        *(float4*)&bias[4] = *(const float4*)(b1 + fc + tx * 8 + 4);
#pragma unroll
        for (int i = 0; i < 8; ++i)
#pragma unroll
            for (int j = 0; j < 8; ++j) {
                const float v = acc[i][j] + bias[j];
                acc[i][j] = 0.5f * v * (1.0f + erff(v * 0.70710678118654752f));
            }

        // ---- second GEMM: partial logits, deterministic in-wave reduce ----
#pragma unroll
        for (int q = 0; q < 4; ++q) {
            float w2q[8][4];
#pragma unroll
            for (int j = 0; j < 8; ++j) {
                const float4 w = *(const float4*)(W2 + (size_t)(fc + tx * 8 + j) * EDIM + q * 4);
                w2q[j][0] = w.x; w2q[j][1] = w.y; w2q[j][2] = w.z; w2q[j][3] = w.w;
            }
            float pe[8][4];
#pragma unroll
            for (int i = 0; i < 8; ++i)
#pragma unroll
                for (int e = 0; e < 4; ++e) {
                    float s = 0.0f;
#pragma unroll
                    for (int j = 0; j < 8; ++j)
                        s = fmaf(acc[i][j], w2q[j][e], s);
                    pe[i][e] = s;
                }
            // butterfly reduce across the 16 tx lanes (lanes ty*16+tx within wave)
#pragma unroll
            for (int m = 1; m < 16; m <<= 1)
#pragma unroll
                for (int i = 0; i < 8; ++i)
#pragma unroll
                    for (int e = 0; e < 4; ++e)
                        pe[i][e] += __shfl_xor(pe[i][e], m, 64);
            if (tx == 0) {
#pragma unroll
                for (int i = 0; i < 8; ++i)
#pragma unroll
                    for (int e = 0; e < 4; ++e)
                        lgt[ty * 8 + i][q * 4 + e] += pe[i][e];
            }
        }
    }

    __syncthreads();

    // ---- softmax + clip + stable top-2 + outputs (1 thread / token) ----
    if (tid < TBLK) {
        const int t = t0 + tid;
        float l[EDIM], p[EDIM];
#pragma unroll
        for (int e = 0; e < EDIM; ++e) l[e] = lgt[tid][e];
        float mx = l[0];
#pragma unroll
        for (int e = 1; e < EDIM; ++e) mx = fmaxf(mx, l[e]);
        float s = 0.0f;
#pragma unroll
        for (int e = 0; e < EDIM; ++e) { p[e] = expf(l[e] - mx); s += p[e]; }
        const float inv = 1.0f / s;
#pragma unroll
        for (int e = 0; e < EDIM; ++e) {
            float v = p[e] * inv;
            v = fminf(fmaxf(v, 1e-9f), 1.0f - 1e-9f);
            p[e] = v;
        }
        // top-1: strict > keeps lowest index on ties (matches lax.top_k)
        int i1 = 0; float v1 = p[0];
#pragma unroll
        for (int e = 1; e < EDIM; ++e) if (p[e] > v1) { v1 = p[e]; i1 = e; }
        // top-2: first (lowest-index) max among the rest
        int i2 = -1; float v2 = -1.0f;
#pragma unroll
        for (int e = 0; e < EDIM; ++e)
            if (e != i1 && p[e] > v2) { v2 = p[e]; i2 = e; }
        const float rs = 1.0f / (v1 + v2);

        float* om  = out + (size_t)t * EDIM;
        float* oi  = out + (size_t)NTOK * 16 + (size_t)t * 2;
        float* orp = out + (size_t)NTOK * 18 + (size_t)t * EDIM;
        float* opf = out + (size_t)NTOK * 34 + (size_t)t * EDIM;
#pragma unroll
        for (int e = 0; e < EDIM; ++e) om[e] = (e == i1 || e == i2) ? 1.0f : 0.0f;
        oi[0] = (float)i1;
        oi[1] = (float)i2;
#pragma unroll
        for (int e = 0; e < EDIM; ++e)
            orp[e] = (e == i1) ? v1 * rs : ((e == i2) ? v2 * rs : 0.0f);
#pragma unroll
        for (int e = 0; e < EDIM; ++e) opf[e] = p[e];
    }
}

extern "C" void kernel_launch(void* const* d_in, const int* in_sizes, int n_in,
                              void* d_out, int out_size, void* d_ws, size_t ws_size,
                              hipStream_t stream)
{
    const float* inp = (const float*)d_in[0];
    const float* cnd = (const float*)d_in[1];
    const float* W1  = (const float*)d_in[2];
    const float* b1  = (const float*)d_in[3];
    const float* W2  = (const float*)d_in[4];
    const float* b2  = (const float*)d_in[5];
    float* out = (float*)d_out;

    dim3 grid(NTOK / TBLK), block(256);
    hipLaunchKernelGGL(router_fused, grid, block, 0, stream,
                       inp, cnd, W1, b1, W2, b2, out);
}